// Round 1
// baseline (179.951 us; speedup 1.0000x reference)
//
#include <hip/hip_runtime.h>
#include <math.h>

// Problem constants (match reference)
#define NVARS   524288
#define WIDTH   524288
#define FANIN   8
#define NEDGES  (WIDTH * FANIN)          // 4194304 per layer
#define ENC_PAD 1048592                  // 2 + 2*NVARS = 1048578, padded to mult of 16

// encode_input: x = [-inf, 0, w0, log1mexp(w0), w1, log1mexp(w1), ...]
__global__ __launch_bounds__(256) void encode_kernel(const float* __restrict__ w,
                                                     float* __restrict__ x) {
    int i = blockIdx.x * blockDim.x + threadIdx.x;
    if (i == 0) { x[0] = -__builtin_inff(); x[1] = 0.0f; }
    if (i < NVARS) {
        float wi = w[i];
        // log1mexp: x > -log2 ? log(-expm1(x)) : log1p(-exp(x))
        float neg = (wi > -0.69314718055994530942f) ? logf(-expm1f(wi))
                                                    : log1pf(-expf(wi));
        x[2 + 2 * i] = wi;
        x[3 + 2 * i] = neg;
    }
}

// SumLayer: y[i] = sum_{k<8} x[ptr[8i+k]]   (log-space product)
__global__ __launch_bounds__(256) void sum_layer(const int* __restrict__ ptr,
                                                 const float* __restrict__ x,
                                                 float* __restrict__ y) {
    int i = blockIdx.x * blockDim.x + threadIdx.x;   // grid sized exactly
    const int4* p = (const int4*)(ptr + (size_t)i * FANIN);
    int4 a = p[0];
    int4 b = p[1];
    float g0 = x[a.x], g1 = x[a.y], g2 = x[a.z], g3 = x[a.w];
    float g4 = x[b.x], g5 = x[b.y], g6 = x[b.z], g7 = x[b.w];
    y[i] = ((g0 + g1) + (g2 + g3)) + ((g4 + g5) + (g6 + g7));
}

// LogSumLayer: stabilized logsumexp over the 8 children.
// All-children -inf  =>  m=-inf  =>  reference yields log(8+eps) + (-inf) = -inf.
__global__ __launch_bounds__(256) void lse_layer(const int* __restrict__ ptr,
                                                 const float* __restrict__ x,
                                                 float* __restrict__ y) {
    int i = blockIdx.x * blockDim.x + threadIdx.x;
    const int4* p = (const int4*)(ptr + (size_t)i * FANIN);
    int4 a = p[0];
    int4 b = p[1];
    float g0 = x[a.x], g1 = x[a.y], g2 = x[a.z], g3 = x[a.w];
    float g4 = x[b.x], g5 = x[b.y], g6 = x[b.z], g7 = x[b.w];
    float m = fmaxf(fmaxf(fmaxf(g0, g1), fmaxf(g2, g3)),
                    fmaxf(fmaxf(g4, g5), fmaxf(g6, g7)));
    float out;
    if (m == -__builtin_inff()) {
        out = -__builtin_inff();
    } else {
        float s = (expf(g0 - m) + expf(g1 - m)) + (expf(g2 - m) + expf(g3 - m))
                + (expf(g4 - m) + expf(g5 - m)) + (expf(g6 - m) + expf(g7 - m))
                + 1e-15f;
        out = logf(s) + m;
    }
    y[i] = out;
}

extern "C" void kernel_launch(void* const* d_in, const int* in_sizes, int n_in,
                              void* d_out, int out_size, void* d_ws, size_t ws_size,
                              hipStream_t stream) {
    const float* w    = (const float*)d_in[0];
    const int*   ptrs = (const int*)d_in[1];   // [8, NEDGES]
    // d_in[2] (csrs) is structurally known: repeat(arange(WIDTH), 8) — unused.
    float* out = (float*)d_out;
    float* ws  = (float*)d_ws;

    float* enc  = ws;                  // 1048578 floats (padded to ENC_PAD)
    float* bufA = ws + ENC_PAD;        // WIDTH floats
    float* bufB = bufA + WIDTH;        // WIDTH floats

    const int  block = 256;
    const int  gridN = NVARS / block;  // 2048 (NVARS divisible by 256)
    const int  gridW = WIDTH / block;  // 2048

    encode_kernel<<<gridN, block, 0, stream>>>(w, enc);

    // Layers: even = sum, odd = logsumexp. Ping-pong A/B; last writes d_out.
    sum_layer<<<gridW, block, 0, stream>>>(ptrs + (size_t)0 * NEDGES, enc,  bufA);
    lse_layer<<<gridW, block, 0, stream>>>(ptrs + (size_t)1 * NEDGES, bufA, bufB);
    sum_layer<<<gridW, block, 0, stream>>>(ptrs + (size_t)2 * NEDGES, bufB, bufA);
    lse_layer<<<gridW, block, 0, stream>>>(ptrs + (size_t)3 * NEDGES, bufA, bufB);
    sum_layer<<<gridW, block, 0, stream>>>(ptrs + (size_t)4 * NEDGES, bufB, bufA);
    lse_layer<<<gridW, block, 0, stream>>>(ptrs + (size_t)5 * NEDGES, bufA, bufB);
    sum_layer<<<gridW, block, 0, stream>>>(ptrs + (size_t)6 * NEDGES, bufB, bufA);
    lse_layer<<<gridW, block, 0, stream>>>(ptrs + (size_t)7 * NEDGES, bufA, out);
}